// Round 2
// 2527.791 us; speedup vs baseline: 1.3386x; 1.3386x over previous
//
#include <hip/hip_runtime.h>
#include <math.h>

#define HH 128
#define WW 128
#define CIN 512
#define NPIX 16384
#define NPRE 6000
#define NPOST 300

// workspace offsets (floats; LOG region is doubles at even float offsets)
#define WS_WT     0ull                        // 2359296 floats (f32 wtT[(c*9+k)][m])
#define WS_LIST   2359296ull                  // 16384 ints (active pixel list)
#define WS_NACT   2375680ull                  // 1 int
#define WS_LOG    4718592ull                  // 16384*12 doubles = 393216 floats
#define WS_FG32   5111808ull                  // 16384
#define WS_ASCALE 5128192ull                  // 16384
#define WS_ASSIGN 5144576ull                  // 16384 (int)
#define WS_ROI    5160960ull                  // 16384*4
#define WS_SC32   5226496ull                  // 16384
#define WS_CAND   5242880ull                  // 6000*4
#define WS_TOPS   5266880ull                  // 6000

// d_out offsets (floats), concatenated tuple in return order
#define O_LOCS   0
#define O_ROIS   65536
#define O_RIDX   66736
#define O_ANCHOR 67036
#define O_CLS    132572
#define O_COS    247260
#define O_RSC    263644
#define O_OLD    263944

typedef double d4 __attribute__((ext_vector_type(4)));

__device__ __forceinline__ float exp32(float x) { return (float)exp((double)x); }
__device__ __forceinline__ float sqrt32(float x) { return (float)sqrt((double)x); }

__global__ __launch_bounds__(1024) void zero_kernel(double* __restrict__ p, int n) {
  int i = blockIdx.x * 1024 + threadIdx.x;
  if (i < n) p[i] = 0.0;
}

// ------- weight transpose: w[m][c][k] (f32) -> wtT[(c*9+k)][m] (f32) ---------
__global__ __launch_bounds__(256) void wt_kernel(const float* __restrict__ w,
                                                 float* __restrict__ wtT) {
  __shared__ float t[64][65];
  int ck0 = blockIdx.x * 64;
  int m0  = blockIdx.y * 64;
  int j  = threadIdx.x & 63;
  int i0 = threadIdx.x >> 6;
#pragma unroll
  for (int ii = 0; ii < 16; ++ii) {
    int i = i0 + ii * 4;
    t[i][j] = w[(size_t)(m0 + i) * 4608 + ck0 + j];
  }
  __syncthreads();
#pragma unroll
  for (int ii = 0; ii < 16; ++ii) {
    int jj = i0 + ii * 4;
    wtT[(size_t)(ck0 + jj) * 512 + m0 + j] = t[j][jj];
  }
}

// ------- compacted active-pixel list, deterministic row-major order ----------
__global__ __launch_bounds__(1024) void alist_kernel(const int* __restrict__ mask,
                                                     int* __restrict__ list,
                                                     int* __restrict__ nact) {
  __shared__ int sc[1024];
  int tid = threadIdx.x;
  int base = tid << 4;
  int m[16];
  int cnt = 0;
#pragma unroll
  for (int i = 0; i < 16; ++i) {
    m[i] = mask[base + i];
    cnt += (m[i] != 0);
  }
  sc[tid] = cnt;
  __syncthreads();
  for (int off = 1; off < 1024; off <<= 1) {
    int v = 0;
    if (tid >= off) v = sc[tid - off];
    __syncthreads();
    sc[tid] += v;
    __syncthreads();
  }
  int pos = sc[tid] - cnt;
#pragma unroll
  for (int i = 0; i < 16; ++i)
    if (m[i] != 0) list[pos++] = base + i;
  if (tid == 1023) nact[0] = sc[1023];
}

// ------- implicit-GEMM conv via fp64 MFMA 16x16x4 + fused heads --------------
// wave = 16 pixels x 64 outch (4 N-frags). A[m=lane&15][k=lane>>4] from x (f32->f64),
// B[k=lane>>4][n=lane&15] from wtT (f32->f64). D (row,col) register mapping is
// PROBED at runtime (2 identity-MFMAs) rather than assumed — f64 D layout is not
// covered by the verified gfx950 dtype-independence claim.
__global__ __launch_bounds__(256) void conv_mfma_kernel(
    const float* __restrict__ x, const float* __restrict__ wtT,
    const float* __restrict__ bias, const float* __restrict__ loc_w,
    const float* __restrict__ cls_w, const float* __restrict__ cos_w,
    const int* __restrict__ list, const int* __restrict__ nact,
    double* __restrict__ logits) {
  int tid = threadIdx.x;
  int lane = tid & 63;
  int wv = tid >> 6;                  // wave 0..3
  int tile = blockIdx.x * 4 + wv;     // 16-pixel tile
  int n = nact[0];
  if (tile * 16 >= n) return;         // wave-uniform exit; kernel has no barriers
  int m0 = blockIdx.y * 64;           // outch group
  int col = lane & 15;
  int kk = lane >> 4;

  // --- probe the D layout: rowmap[r], colmap[r] per lane register ---
  d4 zz = (d4){0.0, 0.0, 0.0, 0.0};
  double pa1 = (kk == 0) ? (double)col : 0.0;   // A[m][0] = m
  double pb1 = (kk == 0) ? 1.0 : 0.0;           // B[0][n] = 1
  d4 rp = __builtin_amdgcn_mfma_f64_16x16x4f64(pa1, pb1, zz, 0, 0, 0);
  double pa2 = (kk == 0) ? 1.0 : 0.0;           // A[m][0] = 1
  double pb2 = (kk == 0) ? (double)col : 0.0;   // B[0][n] = n
  d4 cp = __builtin_amdgcn_mfma_f64_16x16x4f64(pa2, pb2, zz, 0, 0, 0);
  int rowmap[4], colmap[4];
#pragma unroll
  for (int r = 0; r < 4; ++r) {
    rowmap[r] = (int)rp[r];
    colmap[r] = (int)cp[r];
  }

  int slot = tile * 16 + col;         // A-row pixel for this lane
  int p = (slot < n) ? list[slot] : -1;
  bool pv = (p >= 0);
  int py = p >> 7, px = p & 127;

  d4 acc[4];
#pragma unroll
  for (int nf = 0; nf < 4; ++nf) acc[nf] = (d4){0.0, 0.0, 0.0, 0.0};

  for (int j = 0; j < 9; ++j) {
    int dy = j / 3 - 1, dx = j % 3 - 1;
    int yy = py + dy, xx = px + dx;
    bool v = pv && (yy >= 0) && (yy < HH) && (xx >= 0) && (xx < WW);
    int off = v ? (yy * WW + xx) : 0;
    const float* xp = x + (size_t)kk * NPIX + off;
    const float* bp = wtT + (size_t)(kk * 9 + j) * 512 + m0 + col;
#pragma unroll 4
    for (int c0 = 0; c0 < CIN; c0 += 4) {
      float raw = xp[(size_t)c0 * NPIX];
      float av = v ? raw : 0.f;
      double a = (double)av;
      const float* bq = bp + (size_t)c0 * 4608;  // (c0)*9*512
#pragma unroll
      for (int nf = 0; nf < 4; ++nf) {
        double b = (double)bq[nf * 16];
        acc[nf] = __builtin_amdgcn_mfma_f64_16x16x4f64(a, b, acc[nf], 0, 0, 0);
      }
    }
  }

  // Layout-independent epilogue: for reg jj this lane's acc element is
  // D[rowmap[jj]][colmap[jj]] of the 16x64 tile. Apply bias/relu per true col,
  // dot with head weights per true col, reduce the 16 lanes of each kk-group
  // (they jointly cover one full row), write to pixel tile*16+rowmap[jj].
#pragma unroll
  for (int jj = 0; jj < 4; ++jj) {
    int cm = colmap[jj];
    float hvj[4];
#pragma unroll
    for (int nf = 0; nf < 4; ++nf) {
      float bb = bias[m0 + nf * 16 + cm];
      hvj[nf] = fmaxf(__fadd_rn((float)acc[nf][jj], bb), 0.f);
    }
    int s2 = tile * 16 + rowmap[jj];
    bool wr = (col == 0) && (s2 < n);
    int pix = wr ? list[s2] : 0;
#pragma unroll
    for (int r = 0; r < 12; ++r) {
      double t = 0.0;
#pragma unroll
      for (int nf = 0; nf < 4; ++nf) {
        int oc = m0 + nf * 16 + cm;
        float wh = (r < 4) ? loc_w[r * 512 + oc]
                           : (r < 11) ? cls_w[(r - 4) * 512 + oc] : cos_w[oc];
        t += (double)hvj[nf] * (double)wh;
      }
#pragma unroll
      for (int o = 8; o; o >>= 1) t += __shfl_xor(t, o, 16);
      if (wr) atomicAdd(&logits[(size_t)pix * 12 + r], t);
    }
  }
}

// ------- finalize per pixel: f64 softmax/argmax/sigmoid, cast to f32 ----------
__global__ __launch_bounds__(256) void finalize_kernel(
    const double* __restrict__ logits, const float* __restrict__ loc_b,
    const float* __restrict__ cls_b, const float* __restrict__ cos_b,
    float* __restrict__ out, float* __restrict__ fg32,
    float* __restrict__ ascale, int* __restrict__ assign) {
  int p = blockIdx.x * 256 + threadIdx.x;
  const double* lg = &logits[(size_t)p * 12];
#pragma unroll
  for (int o = 0; o < 4; ++o)
    out[O_LOCS + p * 4 + o] = (float)(lg[o] + (double)loc_b[o]);
  double cl[7];
#pragma unroll
  for (int i = 0; i < 7; ++i) {
    cl[i] = lg[4 + i] + (double)cls_b[i];
    out[O_CLS + p * 7 + i] = (float)cl[i];
  }
  double z = lg[11] + (double)cos_b[0];
  double sig = 1.0 / (1.0 + exp(-z));
  out[O_COS + p] = (float)sig;
  double pm = cl[0];
  int ai = 0;
#pragma unroll
  for (int i = 1; i < 7; ++i)
    if (cl[i] > pm) { pm = cl[i]; ai = i; }
  double mx = cl[0];
#pragma unroll
  for (int i = 1; i < 7; ++i) mx = fmax(mx, cl[i]);
  double S = 0.0;
#pragma unroll
  for (int i = 0; i < 7; ++i) S += exp(cl[i] - mx);
  double p0 = exp(cl[0] - mx) / S;
  fg32[p] = (float)(1.0 - p0);
  assign[p] = ai;
  const float BS[7] = {16.f, 9.f, 14.f, 21.f, 33.f, 54.f, 93.f};
  ascale[p] = BS[ai];
}

// -------- anchors, loc2bbox, clip, validity, scores — fp32 op-for-op ----------
__global__ __launch_bounds__(256) void roi_kernel(
    float* __restrict__ out, const float* __restrict__ fg32,
    const float* __restrict__ ascale, const int* __restrict__ assign,
    const int* __restrict__ img_h, const int* __restrict__ img_w,
    float* __restrict__ roi, float* __restrict__ scores32) {
  int p = blockIdx.x * 256 + threadIdx.x;
  float a0 = out[O_COS + 0];
  if (a0 == 0.0f) a0 = __fadd_rn(a0, 1e-5f);
  float t1 = __fmul_rn(a0, a0);
  float t2 = __fdiv_rn(1.0f, t1);
  float t3 = __fsub_rn(t2, 1.0f);
  float anchor_h = __fmul_rn(ascale[0], sqrt32(t3));
  float anchor_w = ascale[p];
  float ay = __fadd_rn((float)(p >> 7) * 8.0f, 4.0f);
  float ax = __fadd_rn((float)(p & 127) * 8.0f, 4.0f);
  float A0 = __fsub_rn(ay, __fmul_rn(0.5f, anchor_h));
  float A1 = __fsub_rn(ax, __fmul_rn(0.5f, anchor_w));
  float A2 = __fadd_rn(ay, __fmul_rn(0.5f, anchor_h));
  float A3 = __fadd_rn(ax, __fmul_rn(0.5f, anchor_w));
  *(float4*)&out[O_ANCHOR + p * 4] = make_float4(A0, A1, A2, A3);
  float hA = __fsub_rn(A2, A0), wA = __fsub_rn(A3, A1);
  float cy = __fadd_rn(A0, __fmul_rn(0.5f, hA));
  float cx = __fadd_rn(A1, __fmul_rn(0.5f, wA));
  float l0 = out[O_LOCS + p * 4 + 0], l1 = out[O_LOCS + p * 4 + 1];
  float l2 = out[O_LOCS + p * 4 + 2], l3 = out[O_LOCS + p * 4 + 3];
  float ncy = __fadd_rn(__fmul_rn(l0, hA), cy);
  float ncx = __fadd_rn(__fmul_rn(l1, wA), cx);
  float nh = __fmul_rn(exp32(l2), hA);
  float nw = __fmul_rn(exp32(l3), wA);
  float b0 = __fsub_rn(ncy, __fmul_rn(0.5f, nh));
  float b1 = __fsub_rn(ncx, __fmul_rn(0.5f, nw));
  float b2 = __fadd_rn(ncy, __fmul_rn(0.5f, nh));
  float b3 = __fadd_rn(ncx, __fmul_rn(0.5f, nw));
  float IH = (float)img_h[0], IW = (float)img_w[0];
  b0 = fminf(fmaxf(b0, 0.f), IH);
  b1 = fminf(fmaxf(b1, 0.f), IW);
  b2 = fminf(fmaxf(b2, 0.f), IH);
  b3 = fminf(fmaxf(b3, 0.f), IW);
  *(float4*)&roi[p * 4] = make_float4(b0, b1, b2, b3);
  float hs = __fsub_rn(b2, b0), wd = __fsub_rn(b3, b1);
  bool valid = (assign[p] > 0) && (hs >= 16.f) && (wd >= 16.f);
  scores32[p] = valid ? fg32[p] : -INFINITY;
}

// ----- stable descending sort (bitonic) on fp32 score bits + index asc -------
__global__ __launch_bounds__(1024) void sort_kernel(
    const float* __restrict__ scores32, const float* __restrict__ roi,
    float* __restrict__ out, float* __restrict__ cand, float* __restrict__ tops) {
  __shared__ unsigned long long keys[16384];
  int tid = threadIdx.x;
  for (int i = tid; i < 16384; i += 1024) {
    unsigned u = __float_as_uint(scores32[i]);
    u = (u & 0x80000000u) ? ~u : (u | 0x80000000u);
    keys[i] = ((unsigned long long)(~u) << 32) | (unsigned)i;
  }
  __syncthreads();
  for (int k = 2; k <= 16384; k <<= 1) {
    for (int j = k >> 1; j > 0; j >>= 1) {
      for (int i = tid; i < 16384; i += 1024) {
        int l = i ^ j;
        if (l > i) {
          unsigned long long a = keys[i], b = keys[l];
          bool up = ((i & k) == 0);
          if ((a > b) == up) { keys[i] = b; keys[l] = a; }
        }
      }
      __syncthreads();
    }
  }
  for (int t = tid; t < NPRE; t += 1024) {
    int idx = (int)(keys[t] & 0x3FFFull);
    float s = scores32[idx];
    float4 b = make_float4(0.f, 0.f, 0.f, 0.f);
    if (isfinite(s)) b = *(const float4*)&roi[idx * 4];
    ((float4*)(out + O_OLD))[t] = b;
    ((float4*)cand)[t] = b;
    tops[t] = s;
  }
}

// --- sequential NMS: boxes in immutable LDS, live scores in registers,
// --- fused suppress+argmax pass, 2 barriers/iter, fp32 op-for-op --------------
__global__ __launch_bounds__(1024) void nms_kernel(const float* __restrict__ cand,
                                                   const float* __restrict__ tops,
                                                   float* __restrict__ out) {
  __shared__ float sy0[NPRE], sx0[NPRE], sy1[NPRE], sx1[NPRE], sar[NPRE], ssc[NPRE];
  __shared__ unsigned long long red[16];
  __shared__ unsigned long long bestk_s;
  int tid = threadIdx.x;
  float rsc[6];
#pragma unroll
  for (int j = 0; j < 6; ++j) {
    int i = tid + j * 1024;
    if (i < NPRE) {
      float4 b = ((const float4*)cand)[i];
      float s = tops[i];
      float ar = __fmul_rn(__fsub_rn(b.z, b.x), __fsub_rn(b.w, b.y));
      sy0[i] = b.x; sx0[i] = b.y; sy1[i] = b.z; sx1[i] = b.w;
      sar[i] = ar; ssc[i] = s;
      rsc[j] = s;
    } else {
      rsc[j] = -INFINITY;
    }
  }
  __syncthreads();
  int lane = tid & 63, wid = tid >> 6;
  float py0 = 0.f, px0 = 0.f, py1 = 0.f, px1 = 0.f, par = 0.f;
  bool havepick = false;
  for (int k = 0; k < NPOST; ++k) {
    unsigned long long best = 0;
#pragma unroll
    for (int j = 0; j < 6; ++j) {
      int i = tid + j * 1024;
      if (i < NPRE) {
        float s = rsc[j];
        if (havepick && s != -INFINITY) {
          float yy0 = fmaxf(sy0[i], py0), xx0 = fmaxf(sx0[i], px0);
          float yy1 = fminf(sy1[i], py1), xx1 = fminf(sx1[i], px1);
          float inter = __fmul_rn(fmaxf(__fsub_rn(yy1, yy0), 0.f),
                                  fmaxf(__fsub_rn(xx1, xx0), 0.f));
          float den = __fadd_rn(__fsub_rn(__fadd_rn(sar[i], par), inter), 1e-9f);
          float iou = __fdiv_rn(inter, den);
          if (iou > 0.7f) { rsc[j] = -INFINITY; s = -INFINITY; }
        }
        unsigned u = __float_as_uint(s);
        u = (u & 0x80000000u) ? ~u : (u | 0x80000000u);
        unsigned long long key =
            ((unsigned long long)u << 32) | (unsigned)(NPRE - i);
        if (key > best) best = key;
      }
    }
#pragma unroll
    for (int off = 32; off; off >>= 1) {
      unsigned long long o = __shfl_xor(best, off, 64);
      if (o > best) best = o;
    }
    if (lane == 0) red[wid] = best;
    __syncthreads();
    if (tid == 0) {
      unsigned long long b = red[0];
      for (int w2 = 1; w2 < 16; ++w2)
        if (red[w2] > b) b = red[w2];
      bestk_s = b;
    }
    __syncthreads();
    unsigned long long b = bestk_s;
    int i = NPRE - (int)(b & 0xFFFFFFFFull);
    bool valid = (unsigned)(b >> 32) > 0x007FFFFFu;
    py0 = sy0[i]; px0 = sx0[i]; py1 = sy1[i]; px1 = sx1[i]; par = sar[i];
    havepick = true;
    if (tid == 0) {
      if (valid) {
        out[O_ROIS + k * 4 + 0] = py0;
        out[O_ROIS + k * 4 + 1] = px0;
        out[O_ROIS + k * 4 + 2] = py1;
        out[O_ROIS + k * 4 + 3] = px1;
        out[O_RSC + k] = ssc[i];
      } else {
        out[O_ROIS + k * 4 + 0] = 0.f;
        out[O_ROIS + k * 4 + 1] = 0.f;
        out[O_ROIS + k * 4 + 2] = 0.f;
        out[O_ROIS + k * 4 + 3] = 0.f;
        out[O_RSC + k] = 0.f;
      }
    }
  }
  for (int t = tid; t < NPOST; t += 1024) out[O_RIDX + t] = 0.f;
}

extern "C" void kernel_launch(void* const* d_in, const int* in_sizes, int n_in,
                              void* d_out, int out_size, void* d_ws, size_t ws_size,
                              hipStream_t stream) {
  (void)in_sizes; (void)n_in; (void)out_size; (void)ws_size;
  const float* x      = (const float*)d_in[0];
  const int*   skel   = (const int*)d_in[1];
  const float* conv_w = (const float*)d_in[2];
  const float* conv_b = (const float*)d_in[3];
  const float* loc_w  = (const float*)d_in[4];
  const float* loc_b  = (const float*)d_in[5];
  const float* cls_w  = (const float*)d_in[6];
  const float* cls_b  = (const float*)d_in[7];
  const float* cos_w  = (const float*)d_in[8];
  const float* cos_b  = (const float*)d_in[9];
  const int*   img_h  = (const int*)d_in[10];
  const int*   img_w  = (const int*)d_in[11];
  float* out = (float*)d_out;
  float* ws  = (float*)d_ws;

  float*  wtT      = ws + WS_WT;
  int*    list     = (int*)(ws + WS_LIST);
  int*    nact     = (int*)(ws + WS_NACT);
  double* logits   = (double*)(ws + WS_LOG);
  float*  fg32     = ws + WS_FG32;
  float*  ascale   = ws + WS_ASCALE;
  int*    assign   = (int*)(ws + WS_ASSIGN);
  float*  roi      = ws + WS_ROI;
  float*  scores32 = ws + WS_SC32;
  float*  cand     = ws + WS_CAND;
  float*  tops     = ws + WS_TOPS;

  hipLaunchKernelGGL(zero_kernel, dim3(192), dim3(1024), 0, stream, logits, NPIX * 12);
  hipLaunchKernelGGL(wt_kernel, dim3(72, 8), dim3(256), 0, stream, conv_w, wtT);
  hipLaunchKernelGGL(alist_kernel, dim3(1), dim3(1024), 0, stream, skel, list, nact);
  hipLaunchKernelGGL(conv_mfma_kernel, dim3(256, 8), dim3(256), 0, stream, x, wtT,
                     conv_b, loc_w, cls_w, cos_w, list, nact, logits);
  hipLaunchKernelGGL(finalize_kernel, dim3(64), dim3(256), 0, stream, logits, loc_b,
                     cls_b, cos_b, out, fg32, ascale, assign);
  hipLaunchKernelGGL(roi_kernel, dim3(64), dim3(256), 0, stream, out, fg32, ascale,
                     assign, img_h, img_w, roi, scores32);
  hipLaunchKernelGGL(sort_kernel, dim3(1), dim3(1024), 0, stream, scores32, roi, out,
                     cand, tops);
  hipLaunchKernelGGL(nms_kernel, dim3(1), dim3(1024), 0, stream, cand, tops, out);
}

// Round 3
// 1753.286 us; speedup vs baseline: 1.9299x; 1.4417x over previous
//
#include <hip/hip_runtime.h>
#include <math.h>

#define HH 128
#define WW 128
#define CIN 512
#define NPIX 16384
#define NPRE 6000
#define NPOST 300

// workspace offsets (floats; LOG region is doubles at even float offsets)
#define WS_WT     0ull                        // 2359296 floats (f32 wt2[(c*9+k)][perm m])
#define WS_LIST   2359296ull                  // 16384 ints (active pixel list)
#define WS_NACT   2375680ull                  // 1 int
#define WS_LOG    4718592ull                  // 16384*12 doubles = 393216 floats
#define WS_FG32   5111808ull                  // 16384
#define WS_ASCALE 5128192ull                  // 16384
#define WS_ASSIGN 5144576ull                  // 16384 (int)
#define WS_ROI    5160960ull                  // 16384*4
#define WS_SC32   5226496ull                  // 16384
#define WS_CAND   5242880ull                  // 6000*4
#define WS_TOPS   5266880ull                  // 6000

// d_out offsets (floats), concatenated tuple in return order
#define O_LOCS   0
#define O_ROIS   65536
#define O_RIDX   66736
#define O_ANCHOR 67036
#define O_CLS    132572
#define O_COS    247260
#define O_RSC    263644
#define O_OLD    263944

typedef double d4 __attribute__((ext_vector_type(4)));

__device__ __forceinline__ float exp32(float x) { return (float)exp((double)x); }
__device__ __forceinline__ float sqrt32(float x) { return (float)sqrt((double)x); }

__global__ __launch_bounds__(1024) void zero_kernel(double* __restrict__ p, int n) {
  int i = blockIdx.x * 1024 + threadIdx.x;
  if (i < n) p[i] = 0.0;
}

// weight transpose+permute: w[m][c][k] (f32) -> wt2[(c*9+k)][g*64 + (m%16)*4 + m/16]
// so that lane(col,kk) of wave g reads its 4 nf B-values as one contiguous float4.
__global__ __launch_bounds__(256) void wt_kernel(const float* __restrict__ w,
                                                 float* __restrict__ wt2) {
  __shared__ float t[64][65];
  int ck0 = blockIdx.x * 64;
  int m0  = blockIdx.y * 64;
  int j  = threadIdx.x & 63;
  int i0 = threadIdx.x >> 6;
#pragma unroll
  for (int ii = 0; ii < 16; ++ii) {
    int i = i0 + ii * 4;
    t[i][j] = w[(size_t)(m0 + i) * 4608 + ck0 + j];
  }
  __syncthreads();
  int jp = ((j & 15) << 2) | (j >> 4);   // permuted m position within 64-group
#pragma unroll
  for (int ii = 0; ii < 16; ++ii) {
    int jj = i0 + ii * 4;
    wt2[(size_t)(ck0 + jj) * 512 + m0 + jp] = t[j][jj];
  }
}

// ------- compacted active-pixel list, deterministic row-major order ----------
__global__ __launch_bounds__(1024) void alist_kernel(const int* __restrict__ mask,
                                                     int* __restrict__ list,
                                                     int* __restrict__ nact) {
  __shared__ int sc[1024];
  int tid = threadIdx.x;
  int base = tid << 4;
  int m[16];
  int cnt = 0;
#pragma unroll
  for (int i = 0; i < 16; ++i) {
    m[i] = mask[base + i];
    cnt += (m[i] != 0);
  }
  sc[tid] = cnt;
  __syncthreads();
  for (int off = 1; off < 1024; off <<= 1) {
    int v = 0;
    if (tid >= off) v = sc[tid - off];
    __syncthreads();
    sc[tid] += v;
    __syncthreads();
  }
  int pos = sc[tid] - cnt;
#pragma unroll
  for (int i = 0; i < 16; ++i)
    if (m[i] != 0) list[pos++] = base + i;
  if (tid == 1023) nact[0] = sc[1023];
}

// ------- implicit-GEMM conv via fp64 MFMA 16x16x4 + fused heads --------------
// wave = 16 pixels x 64 outch (4 N-frags). c-outer/tap-inner loop keeps the
// tile's ~24 x-cache-lines L1-hot across all 9 taps; B is one float4 per lane
// (permuted wt2 layout); loads batched before the 36-MFMA cluster. D layout
// probed at runtime (2 identity MFMAs) as in round 2.
__global__ __launch_bounds__(256, 2) void conv_mfma_kernel(
    const float* __restrict__ x, const float* __restrict__ wt2,
    const float* __restrict__ bias, const float* __restrict__ loc_w,
    const float* __restrict__ cls_w, const float* __restrict__ cos_w,
    const int* __restrict__ list, const int* __restrict__ nact,
    double* __restrict__ logits) {
  int tid = threadIdx.x;
  int lane = tid & 63;
  int wv = tid >> 6;                  // wave 0..3
  int tile = blockIdx.x * 4 + wv;     // 16-pixel tile
  int n = nact[0];
  if (tile * 16 >= n) return;         // wave-uniform exit; kernel has no barriers
  int m0 = blockIdx.y * 64;           // outch group
  int col = lane & 15;
  int kk = lane >> 4;

  // --- probe the D layout: rowmap[r], colmap[r] per lane register ---
  d4 zz = (d4){0.0, 0.0, 0.0, 0.0};
  double pa1 = (kk == 0) ? (double)col : 0.0;   // A[m][0] = m
  double pb1 = (kk == 0) ? 1.0 : 0.0;           // B[0][n] = 1
  d4 rp = __builtin_amdgcn_mfma_f64_16x16x4f64(pa1, pb1, zz, 0, 0, 0);
  double pa2 = (kk == 0) ? 1.0 : 0.0;           // A[m][0] = 1
  double pb2 = (kk == 0) ? (double)col : 0.0;   // B[0][n] = n
  d4 cp = __builtin_amdgcn_mfma_f64_16x16x4f64(pa2, pb2, zz, 0, 0, 0);
  int rowmap[4], colmap[4];
#pragma unroll
  for (int r = 0; r < 4; ++r) {
    rowmap[r] = (int)rp[r];
    colmap[r] = (int)cp[r];
  }

  int slot = tile * 16 + col;         // A-row pixel for this lane
  int p = (slot < n) ? list[slot] : -1;
  bool pv = (p >= 0);
  int py = p >> 7, px = p & 127;

  // per-lane tap offsets + validity, hoisted out of the K loop
  int offj[9];
  bool valj[9];
#pragma unroll
  for (int j = 0; j < 9; ++j) {
    int dy = j / 3 - 1, dx = j % 3 - 1;
    int yy = py + dy, xx = px + dx;
    bool v = pv && (yy >= 0) && (yy < HH) && (xx >= 0) && (xx < WW);
    valj[j] = v;
    offj[j] = v ? (yy * WW + xx) : 0;
  }

  d4 acc[4];
#pragma unroll
  for (int nf = 0; nf < 4; ++nf) acc[nf] = (d4){0.0, 0.0, 0.0, 0.0};

  const float* xk = x + (size_t)kk * NPIX;
  const float* wk = wt2 + (size_t)(kk * 9) * 512 + m0 + (col << 2);

  for (int c0 = 0; c0 < CIN; c0 += 4) {
    const float* xc = xk + (size_t)c0 * NPIX;
    const float* wc = wk + (size_t)c0 * (9 * 512);
    // batch-issue all 18 loads (9 A dwords + 9 B dwordx4) before the MFMA cluster
    float raws[9];
    float4 bvs[9];
#pragma unroll
    for (int j = 0; j < 9; ++j) {
      raws[j] = xc[offj[j]];
      bvs[j] = *(const float4*)(wc + j * 512);
    }
#pragma unroll
    for (int j = 0; j < 9; ++j) {
      float av = valj[j] ? raws[j] : 0.f;
      double a = (double)av;
      acc[0] = __builtin_amdgcn_mfma_f64_16x16x4f64(a, (double)bvs[j].x, acc[0], 0, 0, 0);
      acc[1] = __builtin_amdgcn_mfma_f64_16x16x4f64(a, (double)bvs[j].y, acc[1], 0, 0, 0);
      acc[2] = __builtin_amdgcn_mfma_f64_16x16x4f64(a, (double)bvs[j].z, acc[2], 0, 0, 0);
      acc[3] = __builtin_amdgcn_mfma_f64_16x16x4f64(a, (double)bvs[j].w, acc[3], 0, 0, 0);
    }
  }

  // Layout-independent epilogue: for reg jj this lane's acc element is
  // D[rowmap[jj]][colmap[jj]] of the 16x64 tile. Apply bias/relu per true col,
  // dot with head weights per true col, reduce the 16 lanes of each kk-group
  // (they jointly cover one full row), write to pixel tile*16+rowmap[jj].
#pragma unroll
  for (int jj = 0; jj < 4; ++jj) {
    int cm = colmap[jj];
    float hvj[4];
#pragma unroll
    for (int nf = 0; nf < 4; ++nf) {
      float bb = bias[m0 + nf * 16 + cm];
      hvj[nf] = fmaxf(__fadd_rn((float)acc[nf][jj], bb), 0.f);
    }
    int s2 = tile * 16 + rowmap[jj];
    bool wr = (col == 0) && (s2 < n);
    int pix = wr ? list[s2] : 0;
#pragma unroll
    for (int r = 0; r < 12; ++r) {
      double t = 0.0;
#pragma unroll
      for (int nf = 0; nf < 4; ++nf) {
        int oc = m0 + nf * 16 + cm;
        float wh = (r < 4) ? loc_w[r * 512 + oc]
                           : (r < 11) ? cls_w[(r - 4) * 512 + oc] : cos_w[oc];
        t += (double)hvj[nf] * (double)wh;
      }
#pragma unroll
      for (int o = 8; o; o >>= 1) t += __shfl_xor(t, o, 16);
      if (wr) atomicAdd(&logits[(size_t)pix * 12 + r], t);
    }
  }
}

// ------- finalize per pixel: f64 softmax/argmax/sigmoid, cast to f32 ----------
__global__ __launch_bounds__(256) void finalize_kernel(
    const double* __restrict__ logits, const float* __restrict__ loc_b,
    const float* __restrict__ cls_b, const float* __restrict__ cos_b,
    float* __restrict__ out, float* __restrict__ fg32,
    float* __restrict__ ascale, int* __restrict__ assign) {
  int p = blockIdx.x * 256 + threadIdx.x;
  const double* lg = &logits[(size_t)p * 12];
#pragma unroll
  for (int o = 0; o < 4; ++o)
    out[O_LOCS + p * 4 + o] = (float)(lg[o] + (double)loc_b[o]);
  double cl[7];
#pragma unroll
  for (int i = 0; i < 7; ++i) {
    cl[i] = lg[4 + i] + (double)cls_b[i];
    out[O_CLS + p * 7 + i] = (float)cl[i];
  }
  double z = lg[11] + (double)cos_b[0];
  double sig = 1.0 / (1.0 + exp(-z));
  out[O_COS + p] = (float)sig;
  double pm = cl[0];
  int ai = 0;
#pragma unroll
  for (int i = 1; i < 7; ++i)
    if (cl[i] > pm) { pm = cl[i]; ai = i; }
  double mx = cl[0];
#pragma unroll
  for (int i = 1; i < 7; ++i) mx = fmax(mx, cl[i]);
  double S = 0.0;
#pragma unroll
  for (int i = 0; i < 7; ++i) S += exp(cl[i] - mx);
  double p0 = exp(cl[0] - mx) / S;
  fg32[p] = (float)(1.0 - p0);
  assign[p] = ai;
  const float BS[7] = {16.f, 9.f, 14.f, 21.f, 33.f, 54.f, 93.f};
  ascale[p] = BS[ai];
}

// -------- anchors, loc2bbox, clip, validity, scores — fp32 op-for-op ----------
__global__ __launch_bounds__(256) void roi_kernel(
    float* __restrict__ out, const float* __restrict__ fg32,
    const float* __restrict__ ascale, const int* __restrict__ assign,
    const int* __restrict__ img_h, const int* __restrict__ img_w,
    float* __restrict__ roi, float* __restrict__ scores32) {
  int p = blockIdx.x * 256 + threadIdx.x;
  float a0 = out[O_COS + 0];
  if (a0 == 0.0f) a0 = __fadd_rn(a0, 1e-5f);
  float t1 = __fmul_rn(a0, a0);
  float t2 = __fdiv_rn(1.0f, t1);
  float t3 = __fsub_rn(t2, 1.0f);
  float anchor_h = __fmul_rn(ascale[0], sqrt32(t3));
  float anchor_w = ascale[p];
  float ay = __fadd_rn((float)(p >> 7) * 8.0f, 4.0f);
  float ax = __fadd_rn((float)(p & 127) * 8.0f, 4.0f);
  float A0 = __fsub_rn(ay, __fmul_rn(0.5f, anchor_h));
  float A1 = __fsub_rn(ax, __fmul_rn(0.5f, anchor_w));
  float A2 = __fadd_rn(ay, __fmul_rn(0.5f, anchor_h));
  float A3 = __fadd_rn(ax, __fmul_rn(0.5f, anchor_w));
  *(float4*)&out[O_ANCHOR + p * 4] = make_float4(A0, A1, A2, A3);
  float hA = __fsub_rn(A2, A0), wA = __fsub_rn(A3, A1);
  float cy = __fadd_rn(A0, __fmul_rn(0.5f, hA));
  float cx = __fadd_rn(A1, __fmul_rn(0.5f, wA));
  float l0 = out[O_LOCS + p * 4 + 0], l1 = out[O_LOCS + p * 4 + 1];
  float l2 = out[O_LOCS + p * 4 + 2], l3 = out[O_LOCS + p * 4 + 3];
  float ncy = __fadd_rn(__fmul_rn(l0, hA), cy);
  float ncx = __fadd_rn(__fmul_rn(l1, wA), cx);
  float nh = __fmul_rn(exp32(l2), hA);
  float nw = __fmul_rn(exp32(l3), wA);
  float b0 = __fsub_rn(ncy, __fmul_rn(0.5f, nh));
  float b1 = __fsub_rn(ncx, __fmul_rn(0.5f, nw));
  float b2 = __fadd_rn(ncy, __fmul_rn(0.5f, nh));
  float b3 = __fadd_rn(ncx, __fmul_rn(0.5f, nw));
  float IH = (float)img_h[0], IW = (float)img_w[0];
  b0 = fminf(fmaxf(b0, 0.f), IH);
  b1 = fminf(fmaxf(b1, 0.f), IW);
  b2 = fminf(fmaxf(b2, 0.f), IH);
  b3 = fminf(fmaxf(b3, 0.f), IW);
  *(float4*)&roi[p * 4] = make_float4(b0, b1, b2, b3);
  float hs = __fsub_rn(b2, b0), wd = __fsub_rn(b3, b1);
  bool valid = (assign[p] > 0) && (hs >= 16.f) && (wd >= 16.f);
  scores32[p] = valid ? fg32[p] : -INFINITY;
}

// ----- stable descending sort (bitonic) on fp32 score bits + index asc -------
__global__ __launch_bounds__(1024) void sort_kernel(
    const float* __restrict__ scores32, const float* __restrict__ roi,
    float* __restrict__ out, float* __restrict__ cand, float* __restrict__ tops) {
  __shared__ unsigned long long keys[16384];
  int tid = threadIdx.x;
  for (int i = tid; i < 16384; i += 1024) {
    unsigned u = __float_as_uint(scores32[i]);
    u = (u & 0x80000000u) ? ~u : (u | 0x80000000u);
    keys[i] = ((unsigned long long)(~u) << 32) | (unsigned)i;
  }
  __syncthreads();
  for (int k = 2; k <= 16384; k <<= 1) {
    for (int j = k >> 1; j > 0; j >>= 1) {
      for (int i = tid; i < 16384; i += 1024) {
        int l = i ^ j;
        if (l > i) {
          unsigned long long a = keys[i], b = keys[l];
          bool up = ((i & k) == 0);
          if ((a > b) == up) { keys[i] = b; keys[l] = a; }
        }
      }
      __syncthreads();
    }
  }
  for (int t = tid; t < NPRE; t += 1024) {
    int idx = (int)(keys[t] & 0x3FFFull);
    float s = scores32[idx];
    float4 b = make_float4(0.f, 0.f, 0.f, 0.f);
    if (isfinite(s)) b = *(const float4*)&roi[idx * 4];
    ((float4*)(out + O_OLD))[t] = b;
    ((float4*)cand)[t] = b;
    tops[t] = s;
  }
}

// --- sequential NMS: boxes in immutable LDS, live scores in registers,
// --- fused suppress+argmax pass, 2 barriers/iter, fp32 op-for-op --------------
__global__ __launch_bounds__(1024) void nms_kernel(const float* __restrict__ cand,
                                                   const float* __restrict__ tops,
                                                   float* __restrict__ out) {
  __shared__ float sy0[NPRE], sx0[NPRE], sy1[NPRE], sx1[NPRE], sar[NPRE], ssc[NPRE];
  __shared__ unsigned long long red[16];
  __shared__ unsigned long long bestk_s;
  int tid = threadIdx.x;
  float rsc[6];
#pragma unroll
  for (int j = 0; j < 6; ++j) {
    int i = tid + j * 1024;
    if (i < NPRE) {
      float4 b = ((const float4*)cand)[i];
      float s = tops[i];
      float ar = __fmul_rn(__fsub_rn(b.z, b.x), __fsub_rn(b.w, b.y));
      sy0[i] = b.x; sx0[i] = b.y; sy1[i] = b.z; sx1[i] = b.w;
      sar[i] = ar; ssc[i] = s;
      rsc[j] = s;
    } else {
      rsc[j] = -INFINITY;
    }
  }
  __syncthreads();
  int lane = tid & 63, wid = tid >> 6;
  float py0 = 0.f, px0 = 0.f, py1 = 0.f, px1 = 0.f, par = 0.f;
  bool havepick = false;
  for (int k = 0; k < NPOST; ++k) {
    unsigned long long best = 0;
#pragma unroll
    for (int j = 0; j < 6; ++j) {
      int i = tid + j * 1024;
      if (i < NPRE) {
        float s = rsc[j];
        if (havepick && s != -INFINITY) {
          float yy0 = fmaxf(sy0[i], py0), xx0 = fmaxf(sx0[i], px0);
          float yy1 = fminf(sy1[i], py1), xx1 = fminf(sx1[i], px1);
          float inter = __fmul_rn(fmaxf(__fsub_rn(yy1, yy0), 0.f),
                                  fmaxf(__fsub_rn(xx1, xx0), 0.f));
          float den = __fadd_rn(__fsub_rn(__fadd_rn(sar[i], par), inter), 1e-9f);
          float iou = __fdiv_rn(inter, den);
          if (iou > 0.7f) { rsc[j] = -INFINITY; s = -INFINITY; }
        }
        unsigned u = __float_as_uint(s);
        u = (u & 0x80000000u) ? ~u : (u | 0x80000000u);
        unsigned long long key =
            ((unsigned long long)u << 32) | (unsigned)(NPRE - i);
        if (key > best) best = key;
      }
    }
#pragma unroll
    for (int off = 32; off; off >>= 1) {
      unsigned long long o = __shfl_xor(best, off, 64);
      if (o > best) best = o;
    }
    if (lane == 0) red[wid] = best;
    __syncthreads();
    if (tid == 0) {
      unsigned long long b = red[0];
      for (int w2 = 1; w2 < 16; ++w2)
        if (red[w2] > b) b = red[w2];
      bestk_s = b;
    }
    __syncthreads();
    unsigned long long b = bestk_s;
    int i = NPRE - (int)(b & 0xFFFFFFFFull);
    bool valid = (unsigned)(b >> 32) > 0x007FFFFFu;
    py0 = sy0[i]; px0 = sx0[i]; py1 = sy1[i]; px1 = sx1[i]; par = sar[i];
    havepick = true;
    if (tid == 0) {
      if (valid) {
        out[O_ROIS + k * 4 + 0] = py0;
        out[O_ROIS + k * 4 + 1] = px0;
        out[O_ROIS + k * 4 + 2] = py1;
        out[O_ROIS + k * 4 + 3] = px1;
        out[O_RSC + k] = ssc[i];
      } else {
        out[O_ROIS + k * 4 + 0] = 0.f;
        out[O_ROIS + k * 4 + 1] = 0.f;
        out[O_ROIS + k * 4 + 2] = 0.f;
        out[O_ROIS + k * 4 + 3] = 0.f;
        out[O_RSC + k] = 0.f;
      }
    }
  }
  for (int t = tid; t < NPOST; t += 1024) out[O_RIDX + t] = 0.f;
}

extern "C" void kernel_launch(void* const* d_in, const int* in_sizes, int n_in,
                              void* d_out, int out_size, void* d_ws, size_t ws_size,
                              hipStream_t stream) {
  (void)in_sizes; (void)n_in; (void)out_size; (void)ws_size;
  const float* x      = (const float*)d_in[0];
  const int*   skel   = (const int*)d_in[1];
  const float* conv_w = (const float*)d_in[2];
  const float* conv_b = (const float*)d_in[3];
  const float* loc_w  = (const float*)d_in[4];
  const float* loc_b  = (const float*)d_in[5];
  const float* cls_w  = (const float*)d_in[6];
  const float* cls_b  = (const float*)d_in[7];
  const float* cos_w  = (const float*)d_in[8];
  const float* cos_b  = (const float*)d_in[9];
  const int*   img_h  = (const int*)d_in[10];
  const int*   img_w  = (const int*)d_in[11];
  float* out = (float*)d_out;
  float* ws  = (float*)d_ws;

  float*  wt2      = ws + WS_WT;
  int*    list     = (int*)(ws + WS_LIST);
  int*    nact     = (int*)(ws + WS_NACT);
  double* logits   = (double*)(ws + WS_LOG);
  float*  fg32     = ws + WS_FG32;
  float*  ascale   = ws + WS_ASCALE;
  int*    assign   = (int*)(ws + WS_ASSIGN);
  float*  roi      = ws + WS_ROI;
  float*  scores32 = ws + WS_SC32;
  float*  cand     = ws + WS_CAND;
  float*  tops     = ws + WS_TOPS;

  hipLaunchKernelGGL(zero_kernel, dim3(192), dim3(1024), 0, stream, logits, NPIX * 12);
  hipLaunchKernelGGL(wt_kernel, dim3(72, 8), dim3(256), 0, stream, conv_w, wt2);
  hipLaunchKernelGGL(alist_kernel, dim3(1), dim3(1024), 0, stream, skel, list, nact);
  hipLaunchKernelGGL(conv_mfma_kernel, dim3(256, 8), dim3(256), 0, stream, x, wt2,
                     conv_b, loc_w, cls_w, cos_w, list, nact, logits);
  hipLaunchKernelGGL(finalize_kernel, dim3(64), dim3(256), 0, stream, logits, loc_b,
                     cls_b, cos_b, out, fg32, ascale, assign);
  hipLaunchKernelGGL(roi_kernel, dim3(64), dim3(256), 0, stream, out, fg32, ascale,
                     assign, img_h, img_w, roi, scores32);
  hipLaunchKernelGGL(sort_kernel, dim3(1), dim3(1024), 0, stream, scores32, roi, out,
                     cand, tops);
  hipLaunchKernelGGL(nms_kernel, dim3(1), dim3(1024), 0, stream, cand, tops, out);
}

// Round 5
// 1740.088 us; speedup vs baseline: 1.9445x; 1.0076x over previous
//
#include <hip/hip_runtime.h>
#include <math.h>

#define HH 128
#define WW 128
#define CIN 512
#define NPIX 16384
#define NPRE 6000
#define NPOST 300

// workspace offsets (floats; LOG region is doubles at even float offsets)
#define WS_WT     0ull                        // 2359296 floats (f32 wt2[(c*9+k)][perm m])
#define WS_LIST   2359296ull                  // 16384 ints (active pixel list)
#define WS_NACT   2375680ull                  // 1 int
#define WS_LOG    4718592ull                  // 16384*12 doubles = 393216 floats
#define WS_FG32   5111808ull                  // 16384
#define WS_ASCALE 5128192ull                  // 16384
#define WS_ASSIGN 5144576ull                  // 16384 (int)
#define WS_ROI    5160960ull                  // 16384*4
#define WS_SC32   5226496ull                  // 16384
#define WS_CAND   5242880ull                  // 6000*4
#define WS_TOPS   5266880ull                  // 6000

// d_out offsets (floats), concatenated tuple in return order
#define O_LOCS   0
#define O_ROIS   65536
#define O_RIDX   66736
#define O_ANCHOR 67036
#define O_CLS    132572
#define O_COS    247260
#define O_RSC    263644
#define O_OLD    263944

typedef double d4 __attribute__((ext_vector_type(4)));

__device__ __forceinline__ float exp32(float x) { return (float)exp((double)x); }
__device__ __forceinline__ float sqrt32(float x) { return (float)sqrt((double)x); }

__global__ __launch_bounds__(1024) void zero_kernel(double* __restrict__ p, int n) {
  int i = blockIdx.x * 1024 + threadIdx.x;
  if (i < n) p[i] = 0.0;
}

// weight transpose+permute: w[m][c][k] (f32) -> wt2[(c*9+k)][g*64 + (m%16)*4 + m/16]
// so that lane(col,kk) of a wave on group g reads its 4 nf B-values as one float4.
__global__ __launch_bounds__(256) void wt_kernel(const float* __restrict__ w,
                                                 float* __restrict__ wt2) {
  __shared__ float t[64][65];
  int ck0 = blockIdx.x * 64;
  int m0  = blockIdx.y * 64;
  int j  = threadIdx.x & 63;
  int i0 = threadIdx.x >> 6;
#pragma unroll
  for (int ii = 0; ii < 16; ++ii) {
    int i = i0 + ii * 4;
    t[i][j] = w[(size_t)(m0 + i) * 4608 + ck0 + j];
  }
  __syncthreads();
  int jp = ((j & 15) << 2) | (j >> 4);   // permuted m position within 64-group
#pragma unroll
  for (int ii = 0; ii < 16; ++ii) {
    int jj = i0 + ii * 4;
    wt2[(size_t)(ck0 + jj) * 512 + m0 + jp] = t[j][jj];
  }
}

// ------- compacted active-pixel list, deterministic row-major order ----------
__global__ __launch_bounds__(1024) void alist_kernel(const int* __restrict__ mask,
                                                     int* __restrict__ list,
                                                     int* __restrict__ nact) {
  __shared__ int sc[1024];
  int tid = threadIdx.x;
  int base = tid << 4;
  int m[16];
  int cnt = 0;
#pragma unroll
  for (int i = 0; i < 16; ++i) {
    m[i] = mask[base + i];
    cnt += (m[i] != 0);
  }
  sc[tid] = cnt;
  __syncthreads();
  for (int off = 1; off < 1024; off <<= 1) {
    int v = 0;
    if (tid >= off) v = sc[tid - off];
    __syncthreads();
    sc[tid] += v;
    __syncthreads();
  }
  int pos = sc[tid] - cnt;
#pragma unroll
  for (int i = 0; i < 16; ++i)
    if (m[i] != 0) list[pos++] = base + i;
  if (tid == 1023) nact[0] = sc[1023];
}

// ------- implicit-GEMM conv via fp64 MFMA 16x16x4 + fused heads --------------
// block = ONE 16-pixel tile; its 4 waves = 4 outch groups (grid.y picks which
// half of the 8 groups). All 4 waves gather identical A addresses -> 3 of 4
// hit L1; leading wave prefetches for siblings. c-outer/tap-inner; B is one
// float4 per lane (permuted wt2); D layout probed at runtime.
__global__ __launch_bounds__(256, 4) void conv_mfma_kernel(
    const float* __restrict__ x, const float* __restrict__ wt2,
    const float* __restrict__ bias, const float* __restrict__ loc_w,
    const float* __restrict__ cls_w, const float* __restrict__ cos_w,
    const int* __restrict__ list, const int* __restrict__ nact,
    double* __restrict__ logits) {
  int tid = threadIdx.x;
  int lane = tid & 63;
  int wv = tid >> 6;                  // wave 0..3 -> outch group
  int tile = blockIdx.x;              // 16-pixel tile (one per block)
  int n = nact[0];
  if (tile * 16 >= n) return;         // block-uniform exit; no barriers used
  int m0 = ((blockIdx.y << 2) | wv) << 6;  // outch group base
  int col = lane & 15;
  int kk = lane >> 4;

  // --- probe the D layout: rowmap[r], colmap[r] per lane register ---
  d4 zz = (d4){0.0, 0.0, 0.0, 0.0};
  double pa1 = (kk == 0) ? (double)col : 0.0;   // A[m][0] = m
  double pb1 = (kk == 0) ? 1.0 : 0.0;           // B[0][n] = 1
  d4 rp = __builtin_amdgcn_mfma_f64_16x16x4f64(pa1, pb1, zz, 0, 0, 0);
  double pa2 = (kk == 0) ? 1.0 : 0.0;           // A[m][0] = 1
  double pb2 = (kk == 0) ? (double)col : 0.0;   // B[0][n] = n
  d4 cp = __builtin_amdgcn_mfma_f64_16x16x4f64(pa2, pb2, zz, 0, 0, 0);
  int rowmap[4], colmap[4];
#pragma unroll
  for (int r = 0; r < 4; ++r) {
    rowmap[r] = (int)rp[r];
    colmap[r] = (int)cp[r];
  }

  int slot = tile * 16 + col;         // A-row pixel for this lane
  int p = (slot < n) ? list[slot] : -1;
  bool pv = (p >= 0);
  int py = p >> 7, px = p & 127;

  // per-lane tap offsets + validity, hoisted out of the K loop
  int offj[9];
  bool valj[9];
#pragma unroll
  for (int j = 0; j < 9; ++j) {
    int dy = j / 3 - 1, dx = j % 3 - 1;
    int yy = py + dy, xx = px + dx;
    bool v = pv && (yy >= 0) && (yy < HH) && (xx >= 0) && (xx < WW);
    valj[j] = v;
    offj[j] = v ? (yy * WW + xx) : 0;
  }

  d4 acc[4];
#pragma unroll
  for (int nf = 0; nf < 4; ++nf) acc[nf] = (d4){0.0, 0.0, 0.0, 0.0};

  const float* xk = x + (size_t)kk * NPIX;
  const float* wk = wt2 + (size_t)(kk * 9) * 512 + m0 + (col << 2);

  for (int c0 = 0; c0 < CIN; c0 += 4) {
    const float* xc = xk + (size_t)c0 * NPIX;
    const float* wc = wk + (size_t)c0 * (9 * 512);
    // batch-issue all 18 loads (9 A dwords + 9 B dwordx4) before the MFMA cluster
    float raws[9];
    float4 bvs[9];
#pragma unroll
    for (int j = 0; j < 9; ++j) {
      raws[j] = xc[offj[j]];
      bvs[j] = *(const float4*)(wc + j * 512);
    }
#pragma unroll
    for (int j = 0; j < 9; ++j) {
      float av = valj[j] ? raws[j] : 0.f;
      double a = (double)av;
      acc[0] = __builtin_amdgcn_mfma_f64_16x16x4f64(a, (double)bvs[j].x, acc[0], 0, 0, 0);
      acc[1] = __builtin_amdgcn_mfma_f64_16x16x4f64(a, (double)bvs[j].y, acc[1], 0, 0, 0);
      acc[2] = __builtin_amdgcn_mfma_f64_16x16x4f64(a, (double)bvs[j].z, acc[2], 0, 0, 0);
      acc[3] = __builtin_amdgcn_mfma_f64_16x16x4f64(a, (double)bvs[j].w, acc[3], 0, 0, 0);
    }
  }

  // Layout-independent epilogue: for reg jj this lane's acc element is
  // D[rowmap[jj]][colmap[jj]] of the 16x64 tile. Apply bias/relu per true col,
  // dot with head weights per true col, reduce the 16 lanes of each kk-group
  // (they jointly cover one full row), write to pixel tile*16+rowmap[jj].
#pragma unroll
  for (int jj = 0; jj < 4; ++jj) {
    int cm = colmap[jj];
    float hvj[4];
#pragma unroll
    for (int nf = 0; nf < 4; ++nf) {
      float bb = bias[m0 + nf * 16 + cm];
      hvj[nf] = fmaxf(__fadd_rn((float)acc[nf][jj], bb), 0.f);
    }
    int s2 = tile * 16 + rowmap[jj];
    bool wr = (col == 0) && (s2 < n);
    int pix = wr ? list[s2] : 0;
#pragma unroll
    for (int r = 0; r < 12; ++r) {
      double t = 0.0;
#pragma unroll
      for (int nf = 0; nf < 4; ++nf) {
        int oc = m0 + nf * 16 + cm;
        float wh = (r < 4) ? loc_w[r * 512 + oc]
                           : (r < 11) ? cls_w[(r - 4) * 512 + oc] : cos_w[oc];
        t += (double)hvj[nf] * (double)wh;
      }
#pragma unroll
      for (int o = 8; o; o >>= 1) t += __shfl_xor(t, o, 16);
      if (wr) atomicAdd(&logits[(size_t)pix * 12 + r], t);
    }
  }
}

// ------- finalize per pixel: f64 softmax/argmax/sigmoid, cast to f32 ----------
__global__ __launch_bounds__(256) void finalize_kernel(
    const double* __restrict__ logits, const float* __restrict__ loc_b,
    const float* __restrict__ cls_b, const float* __restrict__ cos_b,
    float* __restrict__ out, float* __restrict__ fg32,
    float* __restrict__ ascale, int* __restrict__ assign) {
  int p = blockIdx.x * 256 + threadIdx.x;
  const double* lg = &logits[(size_t)p * 12];
#pragma unroll
  for (int o = 0; o < 4; ++o)
    out[O_LOCS + p * 4 + o] = (float)(lg[o] + (double)loc_b[o]);
  double cl[7];
#pragma unroll
  for (int i = 0; i < 7; ++i) {
    cl[i] = lg[4 + i] + (double)cls_b[i];
    out[O_CLS + p * 7 + i] = (float)cl[i];
  }
  double z = lg[11] + (double)cos_b[0];
  double sig = 1.0 / (1.0 + exp(-z));
  out[O_COS + p] = (float)sig;
  double pm = cl[0];
  int ai = 0;
#pragma unroll
  for (int i = 1; i < 7; ++i)
    if (cl[i] > pm) { pm = cl[i]; ai = i; }
  double mx = cl[0];
#pragma unroll
  for (int i = 1; i < 7; ++i) mx = fmax(mx, cl[i]);
  double S = 0.0;
#pragma unroll
  for (int i = 0; i < 7; ++i) S += exp(cl[i] - mx);
  double p0 = exp(cl[0] - mx) / S;
  fg32[p] = (float)(1.0 - p0);
  assign[p] = ai;
  const float BS[7] = {16.f, 9.f, 14.f, 21.f, 33.f, 54.f, 93.f};
  ascale[p] = BS[ai];
}

// -------- anchors, loc2bbox, clip, validity, scores — fp32 op-for-op ----------
__global__ __launch_bounds__(256) void roi_kernel(
    float* __restrict__ out, const float* __restrict__ fg32,
    const float* __restrict__ ascale, const int* __restrict__ assign,
    const int* __restrict__ img_h, const int* __restrict__ img_w,
    float* __restrict__ roi, float* __restrict__ scores32) {
  int p = blockIdx.x * 256 + threadIdx.x;
  float a0 = out[O_COS + 0];
  if (a0 == 0.0f) a0 = __fadd_rn(a0, 1e-5f);
  float t1 = __fmul_rn(a0, a0);
  float t2 = __fdiv_rn(1.0f, t1);
  float t3 = __fsub_rn(t2, 1.0f);
  float anchor_h = __fmul_rn(ascale[0], sqrt32(t3));
  float anchor_w = ascale[p];
  float ay = __fadd_rn((float)(p >> 7) * 8.0f, 4.0f);
  float ax = __fadd_rn((float)(p & 127) * 8.0f, 4.0f);
  float A0 = __fsub_rn(ay, __fmul_rn(0.5f, anchor_h));
  float A1 = __fsub_rn(ax, __fmul_rn(0.5f, anchor_w));
  float A2 = __fadd_rn(ay, __fmul_rn(0.5f, anchor_h));
  float A3 = __fadd_rn(ax, __fmul_rn(0.5f, anchor_w));
  *(float4*)&out[O_ANCHOR + p * 4] = make_float4(A0, A1, A2, A3);
  float hA = __fsub_rn(A2, A0), wA = __fsub_rn(A3, A1);
  float cy = __fadd_rn(A0, __fmul_rn(0.5f, hA));
  float cx = __fadd_rn(A1, __fmul_rn(0.5f, wA));
  float l0 = out[O_LOCS + p * 4 + 0], l1 = out[O_LOCS + p * 4 + 1];
  float l2 = out[O_LOCS + p * 4 + 2], l3 = out[O_LOCS + p * 4 + 3];
  float ncy = __fadd_rn(__fmul_rn(l0, hA), cy);
  float ncx = __fadd_rn(__fmul_rn(l1, wA), cx);
  float nh = __fmul_rn(exp32(l2), hA);
  float nw = __fmul_rn(exp32(l3), wA);
  float b0 = __fsub_rn(ncy, __fmul_rn(0.5f, nh));
  float b1 = __fsub_rn(ncx, __fmul_rn(0.5f, nw));
  float b2 = __fadd_rn(ncy, __fmul_rn(0.5f, nh));
  float b3 = __fadd_rn(ncx, __fmul_rn(0.5f, nw));
  float IH = (float)img_h[0], IW = (float)img_w[0];
  b0 = fminf(fmaxf(b0, 0.f), IH);
  b1 = fminf(fmaxf(b1, 0.f), IW);
  b2 = fminf(fmaxf(b2, 0.f), IH);
  b3 = fminf(fmaxf(b3, 0.f), IW);
  *(float4*)&roi[p * 4] = make_float4(b0, b1, b2, b3);
  float hs = __fsub_rn(b2, b0), wd = __fsub_rn(b3, b1);
  bool valid = (assign[p] > 0) && (hs >= 16.f) && (wd >= 16.f);
  scores32[p] = valid ? fg32[p] : -INFINITY;
}

// ----- stable descending sort (bitonic) on fp32 score bits + index asc -------
__global__ __launch_bounds__(1024) void sort_kernel(
    const float* __restrict__ scores32, const float* __restrict__ roi,
    float* __restrict__ out, float* __restrict__ cand, float* __restrict__ tops) {
  __shared__ unsigned long long keys[16384];
  int tid = threadIdx.x;
  for (int i = tid; i < 16384; i += 1024) {
    unsigned u = __float_as_uint(scores32[i]);
    u = (u & 0x80000000u) ? ~u : (u | 0x80000000u);
    keys[i] = ((unsigned long long)(~u) << 32) | (unsigned)i;
  }
  __syncthreads();
  for (int k = 2; k <= 16384; k <<= 1) {
    for (int j = k >> 1; j > 0; j >>= 1) {
      for (int i = tid; i < 16384; i += 1024) {
        int l = i ^ j;
        if (l > i) {
          unsigned long long a = keys[i], b = keys[l];
          bool up = ((i & k) == 0);
          if ((a > b) == up) { keys[i] = b; keys[l] = a; }
        }
      }
      __syncthreads();
    }
  }
  for (int t = tid; t < NPRE; t += 1024) {
    int idx = (int)(keys[t] & 0x3FFFull);
    float s = scores32[idx];
    float4 b = make_float4(0.f, 0.f, 0.f, 0.f);
    if (isfinite(s)) b = *(const float4*)&roi[idx * 4];
    ((float4*)(out + O_OLD))[t] = b;
    ((float4*)cand)[t] = b;
    tops[t] = s;
  }
}

// --- sequential NMS: boxes in immutable LDS, live scores in registers,
// --- fused suppress+argmax pass, 2 barriers/iter, fp32 op-for-op --------------
__global__ __launch_bounds__(1024) void nms_kernel(const float* __restrict__ cand,
                                                   const float* __restrict__ tops,
                                                   float* __restrict__ out) {
  __shared__ float sy0[NPRE], sx0[NPRE], sy1[NPRE], sx1[NPRE], sar[NPRE], ssc[NPRE];
  __shared__ unsigned long long red[16];
  __shared__ unsigned long long bestk_s;
  int tid = threadIdx.x;
  float rsc[6];
#pragma unroll
  for (int j = 0; j < 6; ++j) {
    int i = tid + j * 1024;
    if (i < NPRE) {
      float4 b = ((const float4*)cand)[i];
      float s = tops[i];
      float ar = __fmul_rn(__fsub_rn(b.z, b.x), __fsub_rn(b.w, b.y));
      sy0[i] = b.x; sx0[i] = b.y; sy1[i] = b.z; sx1[i] = b.w;
      sar[i] = ar; ssc[i] = s;
      rsc[j] = s;
    } else {
      rsc[j] = -INFINITY;
    }
  }
  __syncthreads();
  int lane = tid & 63, wid = tid >> 6;
  float py0 = 0.f, px0 = 0.f, py1 = 0.f, px1 = 0.f, par = 0.f;
  bool havepick = false;
  for (int k = 0; k < NPOST; ++k) {
    unsigned long long best = 0;
#pragma unroll
    for (int j = 0; j < 6; ++j) {
      int i = tid + j * 1024;
      if (i < NPRE) {
        float s = rsc[j];
        if (havepick && s != -INFINITY) {
          float yy0 = fmaxf(sy0[i], py0), xx0 = fmaxf(sx0[i], px0);
          float yy1 = fminf(sy1[i], py1), xx1 = fminf(sx1[i], px1);
          float inter = __fmul_rn(fmaxf(__fsub_rn(yy1, yy0), 0.f),
                                  fmaxf(__fsub_rn(xx1, xx0), 0.f));
          float den = __fadd_rn(__fsub_rn(__fadd_rn(sar[i], par), inter), 1e-9f);
          float iou = __fdiv_rn(inter, den);
          if (iou > 0.7f) { rsc[j] = -INFINITY; s = -INFINITY; }
        }
        unsigned u = __float_as_uint(s);
        u = (u & 0x80000000u) ? ~u : (u | 0x80000000u);
        unsigned long long key =
            ((unsigned long long)u << 32) | (unsigned)(NPRE - i);
        if (key > best) best = key;
      }
    }
#pragma unroll
    for (int off = 32; off; off >>= 1) {
      unsigned long long o = __shfl_xor(best, off, 64);
      if (o > best) best = o;
    }
    if (lane == 0) red[wid] = best;
    __syncthreads();
    if (tid == 0) {
      unsigned long long b = red[0];
      for (int w2 = 1; w2 < 16; ++w2)
        if (red[w2] > b) b = red[w2];
      bestk_s = b;
    }
    __syncthreads();
    unsigned long long b = bestk_s;
    int i = NPRE - (int)(b & 0xFFFFFFFFull);
    bool valid = (unsigned)(b >> 32) > 0x007FFFFFu;
    py0 = sy0[i]; px0 = sx0[i]; py1 = sy1[i]; px1 = sx1[i]; par = sar[i];
    havepick = true;
    if (tid == 0) {
      if (valid) {
        out[O_ROIS + k * 4 + 0] = py0;
        out[O_ROIS + k * 4 + 1] = px0;
        out[O_ROIS + k * 4 + 2] = py1;
        out[O_ROIS + k * 4 + 3] = px1;
        out[O_RSC + k] = ssc[i];
      } else {
        out[O_ROIS + k * 4 + 0] = 0.f;
        out[O_ROIS + k * 4 + 1] = 0.f;
        out[O_ROIS + k * 4 + 2] = 0.f;
        out[O_ROIS + k * 4 + 3] = 0.f;
        out[O_RSC + k] = 0.f;
      }
    }
  }
  for (int t = tid; t < NPOST; t += 1024) out[O_RIDX + t] = 0.f;
}

extern "C" void kernel_launch(void* const* d_in, const int* in_sizes, int n_in,
                              void* d_out, int out_size, void* d_ws, size_t ws_size,
                              hipStream_t stream) {
  (void)in_sizes; (void)n_in; (void)out_size; (void)ws_size;
  const float* x      = (const float*)d_in[0];
  const int*   skel   = (const int*)d_in[1];
  const float* conv_w = (const float*)d_in[2];
  const float* conv_b = (const float*)d_in[3];
  const float* loc_w  = (const float*)d_in[4];
  const float* loc_b  = (const float*)d_in[5];
  const float* cls_w  = (const float*)d_in[6];
  const float* cls_b  = (const float*)d_in[7];
  const float* cos_w  = (const float*)d_in[8];
  const float* cos_b  = (const float*)d_in[9];
  const int*   img_h  = (const int*)d_in[10];
  const int*   img_w  = (const int*)d_in[11];
  float* out = (float*)d_out;
  float* ws  = (float*)d_ws;

  float*  wt2      = ws + WS_WT;
  int*    list     = (int*)(ws + WS_LIST);
  int*    nact     = (int*)(ws + WS_NACT);
  double* logits   = (double*)(ws + WS_LOG);
  float*  fg32     = ws + WS_FG32;
  float*  ascale   = ws + WS_ASCALE;
  int*    assign   = (int*)(ws + WS_ASSIGN);
  float*  roi      = ws + WS_ROI;
  float*  scores32 = ws + WS_SC32;
  float*  cand     = ws + WS_CAND;
  float*  tops     = ws + WS_TOPS;

  hipLaunchKernelGGL(zero_kernel, dim3(192), dim3(1024), 0, stream, logits, NPIX * 12);
  hipLaunchKernelGGL(wt_kernel, dim3(72, 8), dim3(256), 0, stream, conv_w, wt2);
  hipLaunchKernelGGL(alist_kernel, dim3(1), dim3(1024), 0, stream, skel, list, nact);
  hipLaunchKernelGGL(conv_mfma_kernel, dim3(1024, 2), dim3(256), 0, stream, x, wt2,
                     conv_b, loc_w, cls_w, cos_w, list, nact, logits);
  hipLaunchKernelGGL(finalize_kernel, dim3(64), dim3(256), 0, stream, logits, loc_b,
                     cls_b, cos_b, out, fg32, ascale, assign);
  hipLaunchKernelGGL(roi_kernel, dim3(64), dim3(256), 0, stream, out, fg32, ascale,
                     assign, img_h, img_w, roi, scores32);
  hipLaunchKernelGGL(sort_kernel, dim3(1), dim3(1024), 0, stream, scores32, roi, out,
                     cand, tops);
  hipLaunchKernelGGL(nms_kernel, dim3(1), dim3(1024), 0, stream, cand, tops, out);
}